// Round 14
// baseline (86.990 us; speedup 1.0000x reference)
//
#include <hip/hip_runtime.h>
#include <math.h>

#define NPTS  10000
#define NS    79            // slices
#define SLICE 128           // 4 j-tiles of 32; NS*SLICE = 10112 (padded y)
#define NYP   (NS * SLICE)  // 10112
#define NYT   316           // y-tiles of 32 (= NS*4 exactly)
#define NXT   313           // x-tiles of 32 (313*32 = 10016, padded x)
#define CAND_EPS 2.5e-3f    // > 2x the split-bf16 approx error bound (~6e-4)

typedef __attribute__((ext_vector_type(8)))  short bf16x8;
typedef __attribute__((ext_vector_type(16))) float f32x16;

// round-to-nearest-even f32 -> bf16 bits, and exact bf16 -> f32
__device__ __forceinline__ unsigned short f2bf(float f) {
    const unsigned int b = __float_as_uint(f);
    return (unsigned short)((b + 0x7FFFu + ((b >> 16) & 1u)) >> 16);
}
__device__ __forceinline__ float bf2f(unsigned short u) {
    return __uint_as_float(((unsigned int)u) << 16);
}

// ---------------------------------------------------------------------------
// Pack pass (unchanged from R13, verified absmax 0.0): MFMA operands, K=16,
// 11 slots used. dot = xh*yh + xl*yh + xh*yl + hy, error <= ~6e-4.
// Layout: pk[c][tile][khalf][col32][8 u16]; lane l reads its fragment as one
// contiguous 16B chunk. Pad y rows get slot9 = bf16(-60000) -> never win.
// ---------------------------------------------------------------------------
__global__ __launch_bounds__(256) void pack_xy(
    const float* __restrict__ pred_pts, const float* __restrict__ targ_pts,
    unsigned short* __restrict__ ypk, unsigned short* __restrict__ xpk)
{
    const int idx = blockIdx.x * 256 + threadIdx.x;
    const int YTOT = 4 * NYP;
    if (idx < YTOT) {
        const int c = idx / NYP, j = idx - c * NYP;
        const int dir = c >> 1, b = c & 1;
        const float* yp = (dir == 0 ? pred_pts : targ_pts) + (size_t)b * NPTS * 3;
        unsigned short v[16];
#pragma unroll
        for (int e = 0; e < 16; ++e) v[e] = 0;
        if (j < NPTS) {
            const float a = yp[j*3+0], bb = yp[j*3+1], cc = yp[j*3+2];
            const float hy = -0.5f * fmaf(cc, cc, fmaf(bb, bb, a * a));
            const unsigned short ah = f2bf(a), bh = f2bf(bb), ch = f2bf(cc);
            v[0] = ah; v[1] = bh; v[2] = ch;
            v[3] = ah; v[4] = bh; v[5] = ch;
            v[6] = f2bf(a  - bf2f(ah));
            v[7] = f2bf(bb - bf2f(bh));
            v[8] = f2bf(cc - bf2f(ch));
            const unsigned short hh = f2bf(hy);
            v[9] = hh; v[10] = f2bf(hy - bf2f(hh));
        } else {
            v[9] = f2bf(-60000.0f);
        }
        const int jt = j >> 5, col = j & 31;
        unsigned short* d0 = ypk + ((((size_t)c*NYT + jt)*2 + 0)*32 + col)*8;
        unsigned short* d1 = ypk + ((((size_t)c*NYT + jt)*2 + 1)*32 + col)*8;
#pragma unroll
        for (int e = 0; e < 8; ++e) { d0[e] = v[e]; d1[e] = v[8+e]; }
    } else if (idx < YTOT + 4 * NXT * 32) {
        const int idx2 = idx - YTOT;
        const int c = idx2 / (NXT*32), r = idx2 - c * (NXT*32);
        const int dir = c >> 1, b = c & 1;
        const float* xp = (dir == 0 ? targ_pts : pred_pts) + (size_t)b * NPTS * 3;
        const int n = (r < NPTS) ? r : (NPTS - 1);     // clamp; store-masked later
        const float a = xp[n*3+0], bb = xp[n*3+1], cc = xp[n*3+2];
        unsigned short v[16];
#pragma unroll
        for (int e = 0; e < 16; ++e) v[e] = 0;
        const unsigned short ah = f2bf(a), bh = f2bf(bb), ch = f2bf(cc);
        v[0] = ah; v[1] = bh; v[2] = ch;
        v[3] = f2bf(a  - bf2f(ah));
        v[4] = f2bf(bb - bf2f(bh));
        v[5] = f2bf(cc - bf2f(ch));
        v[6] = ah; v[7] = bh; v[8] = ch;
        v[9] = f2bf(1.0f); v[10] = f2bf(1.0f);
        const int xt = r >> 5, col = r & 31;
        unsigned short* d0 = xpk + ((((size_t)c*NXT + xt)*2 + 0)*32 + col)*8;
        unsigned short* d1 = xpk + ((((size_t)c*NXT + xt)*2 + 1)*32 + col)*8;
#pragma unroll
        for (int e = 0; e < 8; ++e) { d0[e] = v[e]; d1[e] = v[8+e]; }
    }
}

// ---------------------------------------------------------------------------
// Pass A (MFMA, re-shaped): block = 4 waves, one (combo, slice); NO LDS, no
// barrier. Each wave keeps the slice's 4 y-fragments in REGISTERS (loaded
// once, L1-shared across waves) and loops over 8 x-tiles: load xf (1 KB
// coalesced), 4x mfma_f32_32x32x16_bf16, fold 16 accs via v_max3, one
// shfl_xor(32), 128 B coalesced store of the approx slice-max.
// 3160 blocks x 128 MFMA/block: work-per-block 32x R13's, latency amortized.
// ---------------------------------------------------------------------------
__global__ __launch_bounds__(256) void knn_mfma(
    const unsigned short* __restrict__ ypk,
    const unsigned short* __restrict__ xpk,
    float* __restrict__ wsM)
{
    const int c  = blockIdx.z;
    const int s  = blockIdx.y;
    const int wv = threadIdx.x >> 6;
    const int l  = threadIdx.x & 63;
    const int kh = l >> 5, col = l & 31;

    bf16x8 yf[4];
#pragma unroll
    for (int jt = 0; jt < 4; ++jt)
        yf[jt] = *(const bf16x8*)(ypk +
            ((((size_t)c*NYT + s*4 + jt)*2 + kh)*32 + col)*8);

    f32x16 zero;
#pragma unroll
    for (int i = 0; i < 16; ++i) zero[i] = 0.0f;

    const int xt0 = (blockIdx.x * 4 + wv) * 8;     // 8 x-tiles per wave
#pragma unroll
    for (int t = 0; t < 8; ++t) {
        const int xt = xt0 + t;
        if (xt < NXT) {
            const bf16x8 xf = *(const bf16x8*)(xpk +
                ((((size_t)c*NXT + xt)*2 + kh)*32 + col)*8);
            float best = -1e30f;
#pragma unroll
            for (int jt = 0; jt < 4; ++jt) {
                const f32x16 d =
                    __builtin_amdgcn_mfma_f32_32x32x16_bf16(yf[jt], xf, zero, 0, 0, 0);
#pragma unroll
                for (int i = 0; i < 16; i += 2)
                    best = fmaxf(best, fmaxf(d[i], d[i+1]));   // -> v_max3_f32
            }
            best = fmaxf(best, __shfl_xor(best, 32));          // fold y halves
            const int x = xt*32 + col;
            if (l < 32 && x < NPTS)
                wsM[((size_t)c*NS + s)*NPTS + x] = best;       // coalesced 128B
        }
    }
}

// ---------------------------------------------------------------------------
// Pass B (unchanged from R13, verified): 16-lane group per x-point. Group-max
// of the 79 approx slice maxima; EXACT fp32 rescan of every slice within
// CAND_EPS (provably contains the winner). Strict > + tie->smaller j ==
// exact first-occurrence argmax. Lane 0: Welsch + normal terms; block-reduce.
// ---------------------------------------------------------------------------
__global__ __launch_bounds__(256) void finalize(
    const float* __restrict__ pred_pts, const float* __restrict__ pred_nrm,
    const float* __restrict__ targ_pts, const float* __restrict__ targ_nrm,
    const float* __restrict__ wsM, float2* __restrict__ wsB)
{
    const int c   = blockIdx.y;
    const int dir = c >> 1, b = c & 1;
    const float* xp = (dir == 0 ? targ_pts : pred_pts) + (size_t)b * NPTS * 3;
    const float* xn = (dir == 0 ? targ_nrm : pred_nrm) + (size_t)b * NPTS * 3;
    const float* yp = (dir == 0 ? pred_pts : targ_pts) + (size_t)b * NPTS * 3;
    const float* yn = (dir == 0 ? pred_nrm : targ_nrm) + (size_t)b * NPTS * 3;

    const int lane  = threadIdx.x & 15;
    const int n     = blockIdx.x * 16 + (threadIdx.x >> 4);   // 625*16 = 10000
    const int gbase = (threadIdx.x & 63) & ~15;               // group base in wave

    float v[5];
    float bm = -1e30f;
#pragma unroll
    for (int k = 0; k < 5; ++k) {
        const int s = lane + 16*k;
        v[k] = (s < NS) ? wsM[((size_t)c*NS + s)*NPTS + n] : -1e30f;
        bm = fmaxf(bm, v[k]);
    }
#pragma unroll
    for (int w = 1; w < 16; w <<= 1)
        bm = fmaxf(bm, __shfl_xor(bm, w, 16));

    const float a  = xp[n*3+0];
    const float bb = xp[n*3+1];
    const float cc = xp[n*3+2];
    const float thr = bm - CAND_EPS;

    float rb  = -1e30f;
    int bidx  = 1 << 30;
#pragma unroll
    for (int k = 0; k < 5; ++k) {
        const unsigned long long full = __ballot(v[k] >= thr);
        unsigned g = (unsigned)((full >> gbase) & 0xFFFFull);
        while (g) {
            const int bpos = __ffs(g) - 1;
            g &= g - 1;
            const int s  = 16*k + bpos;
            const int j0 = s * SLICE;
            const int jend = min(j0 + SLICE, NPTS);
            for (int j = j0 + lane; j < jend; j += 16) {
                const float ya = yp[j*3+0];
                const float yb = yp[j*3+1];
                const float yc = yp[j*3+2];
                const float hy = -0.5f * fmaf(yc, yc, fmaf(yb, yb, ya*ya));
                const float m  = fmaf(a, ya, fmaf(bb, yb, fmaf(cc, yc, hy)));
                if (m > rb || (m == rb && j < bidx)) { rb = m; bidx = j; }
            }
        }
    }
#pragma unroll
    for (int w = 1; w < 16; w <<= 1) {
        const float mo = __shfl_xor(rb, w, 16);
        const int   jo = __shfl_xor(bidx, w, 16);
        if (mo > rb || (mo == rb && jo < bidx)) { rb = mo; bidx = jo; }
    }

    float t0 = 0.f, t1 = 0.f;
    if (lane == 0) {
        const float hx = -0.5f * fmaf(cc, cc, fmaf(bb, bb, a*a));
        float d2 = -2.0f * (rb + hx);
        d2 = fmaxf(d2, 0.0f);
        const float w = __expf(-(d2 * d2) * (1.0f / 0.18f));   // 2*ALPHA^2
        t0 = w * d2;
        const float nx0 = xn[n*3+0], nx1 = xn[n*3+1], nx2 = xn[n*3+2];
        const float ny0 = yn[(size_t)bidx*3+0];
        const float ny1 = yn[(size_t)bidx*3+1];
        const float ny2 = yn[(size_t)bidx*3+2];
        const float nnx = fmaxf(sqrtf(nx0*nx0 + nx1*nx1 + nx2*nx2), 1e-6f);
        const float nny = fmaxf(sqrtf(ny0*ny0 + ny1*ny1 + ny2*ny2), 1e-6f);
        const float cosv = (nx0*ny0 + nx1*ny1 + nx2*ny2) / (nnx * nny);
        t1 = 1.0f - fabsf(cosv);
    }

    __shared__ float r0[256], r1[256];
    r0[threadIdx.x] = t0;
    r1[threadIdx.x] = t1;
    __syncthreads();
    for (int st = 128; st > 0; st >>= 1) {
        if (threadIdx.x < st) {
            r0[threadIdx.x] += r0[threadIdx.x + st];
            r1[threadIdx.x] += r1[threadIdx.x + st];
        }
        __syncthreads();
    }
    if (threadIdx.x == 0)
        wsB[blockIdx.y * gridDim.x + blockIdx.x] = make_float2(r0[0], r1[0]);
}

// ---------------------------------------------------------------------------
// Final deterministic reduction of the 2500 block partials.
// ---------------------------------------------------------------------------
__global__ __launch_bounds__(256) void reduce_final(
    const float2* __restrict__ wsB, int nblocks, float* __restrict__ out)
{
    __shared__ float r0[256], r1[256];
    const int t = threadIdx.x;
    float s0 = 0.f, s1 = 0.f;
    for (int i = t; i < nblocks; i += 256) {
        const float2 v = wsB[i];
        s0 += v.x;
        s1 += v.y;
    }
    r0[t] = s0; r1[t] = s1;
    __syncthreads();
    for (int st = 128; st > 0; st >>= 1) {
        if (t < st) { r0[t] += r0[t + st]; r1[t] += r1[t + st]; }
        __syncthreads();
    }
    if (t == 0) {
        out[0] = 0.5f * r0[0];                 // mean over B=2 of per-batch sums
        out[1] = r1[0] * (1.0f / 20000.0f);    // mean over B*N, both dirs
    }
}

extern "C" void kernel_launch(void* const* d_in, const int* in_sizes, int n_in,
                              void* d_out, int out_size, void* d_ws, size_t ws_size,
                              hipStream_t stream)
{
    const float* pred_pts = (const float*)d_in[0];
    const float* pred_nrm = (const float*)d_in[1];
    const float* targ_pts = (const float*)d_in[2];
    const float* targ_nrm = (const float*)d_in[3];
    float* out = (float*)d_out;

    // workspace carve (total ~15.3 MB of ~256 MB)
    unsigned short* ypk = (unsigned short*)d_ws;            // 4*316*512 u16
    unsigned short* xpk = ypk + (size_t)4 * NYT * 512;      // 4*313*512 u16
    float* wsM  = (float*)(xpk + (size_t)4 * NXT * 512);    // 4*79*10000 f32
    float2* wsB = (float2*)(wsM + (size_t)4 * NS * NPTS);   // 2500 float2

    const int PTOT = 4 * NYP + 4 * NXT * 32;                // 80512 pack threads
    pack_xy<<<(PTOT + 255) / 256, 256, 0, stream>>>(pred_pts, targ_pts, ypk, xpk);

    dim3 gA(10, NS, 4);                 // 10 x-groups (32 tiles) x 79 x 4
    knn_mfma<<<gA, 256, 0, stream>>>(ypk, xpk, wsM);

    dim3 gB(NPTS / 16, 4);              // 625 x 4
    finalize<<<gB, 256, 0, stream>>>(pred_pts, pred_nrm, targ_pts, targ_nrm,
                                     wsM, wsB);

    reduce_final<<<1, 256, 0, stream>>>(wsB, (NPTS / 16) * 4, out);
}

// Round 15
// 78.904 us; speedup vs baseline: 1.1025x; 1.1025x over previous
//
#include <hip/hip_runtime.h>
#include <math.h>

#define NPTS  10000
#define NS    79            // slices
#define SLICE 128           // 4 j-tiles of 32; NS*SLICE = 10112 (padded y)
#define NYP   (NS * SLICE)  // 10112
#define NYT   316           // y-tiles of 32 (= NS*4 exactly)
#define NXT   313           // real x-tiles of 32 (313*32 = 10016)
#define NXT2  320           // padded x-tiles (10*4*8) -> unguarded loads
#define CAND_EPS 2.5e-3f    // > 2x the split-bf16 approx error bound (~6e-4)

typedef __attribute__((ext_vector_type(8)))  short bf16x8;
typedef __attribute__((ext_vector_type(16))) float f32x16;

// round-to-nearest-even f32 -> bf16 bits, and exact bf16 -> f32
__device__ __forceinline__ unsigned short f2bf(float f) {
    const unsigned int b = __float_as_uint(f);
    return (unsigned short)((b + 0x7FFFu + ((b >> 16) & 1u)) >> 16);
}
__device__ __forceinline__ float bf2f(unsigned short u) {
    return __uint_as_float(((unsigned int)u) << 16);
}

// ---------------------------------------------------------------------------
// Pack pass (verified absmax 0.0 in R13/R14): MFMA operands, K=16, 11 slots.
// dot = xh*yh + xl*yh + xh*yl + hy, |err| <= ~6e-4. Layout:
// pk[c][tile][khalf][col32][8 u16]; lane fragment = one contiguous 16B chunk.
// Pad y rows: slot9 = bf16(-60000) -> never win. Pad x cols (NXT..NXT2):
// clamped real values, outputs masked on store.
// ---------------------------------------------------------------------------
__global__ __launch_bounds__(256) void pack_xy(
    const float* __restrict__ pred_pts, const float* __restrict__ targ_pts,
    unsigned short* __restrict__ ypk, unsigned short* __restrict__ xpk)
{
    const int idx = blockIdx.x * 256 + threadIdx.x;
    const int YTOT = 4 * NYP;
    if (idx < YTOT) {
        const int c = idx / NYP, j = idx - c * NYP;
        const int dir = c >> 1, b = c & 1;
        const float* yp = (dir == 0 ? pred_pts : targ_pts) + (size_t)b * NPTS * 3;
        unsigned short v[16];
#pragma unroll
        for (int e = 0; e < 16; ++e) v[e] = 0;
        if (j < NPTS) {
            const float a = yp[j*3+0], bb = yp[j*3+1], cc = yp[j*3+2];
            const float hy = -0.5f * fmaf(cc, cc, fmaf(bb, bb, a * a));
            const unsigned short ah = f2bf(a), bh = f2bf(bb), ch = f2bf(cc);
            v[0] = ah; v[1] = bh; v[2] = ch;
            v[3] = ah; v[4] = bh; v[5] = ch;
            v[6] = f2bf(a  - bf2f(ah));
            v[7] = f2bf(bb - bf2f(bh));
            v[8] = f2bf(cc - bf2f(ch));
            const unsigned short hh = f2bf(hy);
            v[9] = hh; v[10] = f2bf(hy - bf2f(hh));
        } else {
            v[9] = f2bf(-60000.0f);
        }
        const int jt = j >> 5, col = j & 31;
        unsigned short* d0 = ypk + ((((size_t)c*NYT + jt)*2 + 0)*32 + col)*8;
        unsigned short* d1 = ypk + ((((size_t)c*NYT + jt)*2 + 1)*32 + col)*8;
#pragma unroll
        for (int e = 0; e < 8; ++e) { d0[e] = v[e]; d1[e] = v[8+e]; }
    } else if (idx < YTOT + 4 * NXT2 * 32) {
        const int idx2 = idx - YTOT;
        const int c = idx2 / (NXT2*32), r = idx2 - c * (NXT2*32);
        const int dir = c >> 1, b = c & 1;
        const float* xp = (dir == 0 ? targ_pts : pred_pts) + (size_t)b * NPTS * 3;
        const int n = (r < NPTS) ? r : (NPTS - 1);     // clamp; store-masked later
        const float a = xp[n*3+0], bb = xp[n*3+1], cc = xp[n*3+2];
        unsigned short v[16];
#pragma unroll
        for (int e = 0; e < 16; ++e) v[e] = 0;
        const unsigned short ah = f2bf(a), bh = f2bf(bb), ch = f2bf(cc);
        v[0] = ah; v[1] = bh; v[2] = ch;
        v[3] = f2bf(a  - bf2f(ah));
        v[4] = f2bf(bb - bf2f(bh));
        v[5] = f2bf(cc - bf2f(ch));
        v[6] = ah; v[7] = bh; v[8] = ch;
        v[9] = f2bf(1.0f); v[10] = f2bf(1.0f);
        const int xt = r >> 5, col = r & 31;
        unsigned short* d0 = xpk + ((((size_t)c*NXT2 + xt)*2 + 0)*32 + col)*8;
        unsigned short* d1 = xpk + ((((size_t)c*NXT2 + xt)*2 + 1)*32 + col)*8;
#pragma unroll
        for (int e = 0; e < 8; ++e) { d0[e] = v[e]; d1[e] = v[8+e]; }
    }
}

// ---------------------------------------------------------------------------
// Pass A (MFMA v3): block = 4 waves, one (combo, slice). Wave owns 8 x-tiles.
// ALL loads unguarded (x padded to 320 tiles) -> compiler hoists/pipelines;
// xf double-buffered one ahead. Per x-tile: 4 MFMAs with per-jt INDEPENDENT
// tree folds (4-way ILP, v_max3-fusable), one shfl_xor(32), masked store.
// ---------------------------------------------------------------------------
__global__ __launch_bounds__(256) void knn_mfma(
    const unsigned short* __restrict__ ypk,
    const unsigned short* __restrict__ xpk,
    float* __restrict__ wsM)
{
    const int c  = blockIdx.z;
    const int s  = blockIdx.y;
    const int wv = threadIdx.x >> 6;
    const int l  = threadIdx.x & 63;
    const int kh = l >> 5, col = l & 31;

    bf16x8 yf[4];
#pragma unroll
    for (int jt = 0; jt < 4; ++jt)
        yf[jt] = *(const bf16x8*)(ypk +
            ((((size_t)c*NYT + s*4 + jt)*2 + kh)*32 + col)*8);

    f32x16 zero;
#pragma unroll
    for (int i = 0; i < 16; ++i) zero[i] = 0.0f;

    const int xt0 = (blockIdx.x * 4 + wv) * 8;     // 8 x-tiles per wave
    const unsigned short* xbase = xpk + (((size_t)c*NXT2 + xt0)*2 + kh)*256 + col*8;

    bf16x8 xf = *(const bf16x8*)(xbase);           // tile xt0
#pragma unroll
    for (int t = 0; t < 8; ++t) {
        // prefetch next tile (pad guarantees in-bounds; result unused at t=7)
        const bf16x8 xfn = *(const bf16x8*)(xbase + (size_t)(t < 7 ? t + 1 : t) * 512);
        float m[4];
#pragma unroll
        for (int jt = 0; jt < 4; ++jt) {
            const f32x16 d =
                __builtin_amdgcn_mfma_f32_32x32x16_bf16(yf[jt], xf, zero, 0, 0, 0);
            const float u0 = fmaxf(fmaxf(d[0],  d[1]),  fmaxf(d[2],  d[3]));
            const float u1 = fmaxf(fmaxf(d[4],  d[5]),  fmaxf(d[6],  d[7]));
            const float u2 = fmaxf(fmaxf(d[8],  d[9]),  fmaxf(d[10], d[11]));
            const float u3 = fmaxf(fmaxf(d[12], d[13]), fmaxf(d[14], d[15]));
            m[jt] = fmaxf(fmaxf(u0, u1), fmaxf(u2, u3));
        }
        float best = fmaxf(fmaxf(m[0], m[1]), fmaxf(m[2], m[3]));
        best = fmaxf(best, __shfl_xor(best, 32));          // fold y halves
        const int x = (xt0 + t)*32 + col;
        if (l < 32 && x < NPTS)
            wsM[((size_t)c*NS + s)*NPTS + x] = best;       // coalesced 128B
        xf = xfn;
    }
}

// ---------------------------------------------------------------------------
// Pass B (v2): 16-lane group per x-point; 16 x per block.
//   0) COOPERATIVE coalesced stage of the 79x16 slice-max tile into LDS
//      (stride-17 padding -> conflict-free reads). Fixes the R14 gather.
//   1) group-max bm of the 79 approx maxima (reads from LDS).
//   2) EXACT fp32 rescan of every slice within CAND_EPS of bm (provably
//      contains the winner). Strict > + tie->smaller j == exact
//      first-occurrence argmax.
//   3) lane 0: Welsch + normal terms; block-reduce to float2.
// ---------------------------------------------------------------------------
__global__ __launch_bounds__(256) void finalize(
    const float* __restrict__ pred_pts, const float* __restrict__ pred_nrm,
    const float* __restrict__ targ_pts, const float* __restrict__ targ_nrm,
    const float* __restrict__ wsM, float2* __restrict__ wsB)
{
    const int c   = blockIdx.y;
    const int dir = c >> 1, b = c & 1;
    const float* xp = (dir == 0 ? targ_pts : pred_pts) + (size_t)b * NPTS * 3;
    const float* xn = (dir == 0 ? targ_nrm : pred_nrm) + (size_t)b * NPTS * 3;
    const float* yp = (dir == 0 ? pred_pts : targ_pts) + (size_t)b * NPTS * 3;
    const float* yn = (dir == 0 ? pred_nrm : targ_nrm) + (size_t)b * NPTS * 3;

    const int lane  = threadIdx.x & 15;
    const int xg    = threadIdx.x >> 4;                   // group id: 0..15
    const int n0    = blockIdx.x * 16;
    const int n     = n0 + xg;                            // 625*16 = 10000
    const int gbase = (threadIdx.x & 63) & ~15;           // group base in wave

    __shared__ float sq[NS * 17];                         // stride 17: no conflicts

    // 0) coalesced stage: consecutive threads -> consecutive n
    for (int i = threadIdx.x; i < NS * 16; i += 256) {
        const int s = i >> 4, g = i & 15;
        sq[s * 17 + g] = wsM[((size_t)c*NS + s)*NPTS + n0 + g];
    }
    __syncthreads();

    // 1) approx slice maxima + group max
    float v[5];
    float bm = -1e30f;
#pragma unroll
    for (int k = 0; k < 5; ++k) {
        const int s = lane + 16*k;
        v[k] = (s < NS) ? sq[s * 17 + xg] : -1e30f;
        bm = fmaxf(bm, v[k]);
    }
#pragma unroll
    for (int w = 1; w < 16; w <<= 1)
        bm = fmaxf(bm, __shfl_xor(bm, w, 16));

    const float a  = xp[n*3+0];
    const float bb = xp[n*3+1];
    const float cc = xp[n*3+2];
    const float thr = bm - CAND_EPS;

    // 2) exact rescan of candidate slices
    float rb  = -1e30f;
    int bidx  = 1 << 30;
#pragma unroll
    for (int k = 0; k < 5; ++k) {
        const unsigned long long full = __ballot(v[k] >= thr);
        unsigned g = (unsigned)((full >> gbase) & 0xFFFFull);
        while (g) {
            const int bpos = __ffs(g) - 1;
            g &= g - 1;
            const int s  = 16*k + bpos;
            const int j0 = s * SLICE;
            const int jend = min(j0 + SLICE, NPTS);
            for (int j = j0 + lane; j < jend; j += 16) {
                const float ya = yp[j*3+0];
                const float yb = yp[j*3+1];
                const float yc = yp[j*3+2];
                const float hy = -0.5f * fmaf(yc, yc, fmaf(yb, yb, ya*ya));
                const float m  = fmaf(a, ya, fmaf(bb, yb, fmaf(cc, yc, hy)));
                if (m > rb || (m == rb && j < bidx)) { rb = m; bidx = j; }
            }
        }
    }
#pragma unroll
    for (int w = 1; w < 16; w <<= 1) {
        const float mo = __shfl_xor(rb, w, 16);
        const int   jo = __shfl_xor(bidx, w, 16);
        if (mo > rb || (mo == rb && jo < bidx)) { rb = mo; bidx = jo; }
    }

    // 3) terms on lane 0
    float t0 = 0.f, t1 = 0.f;
    if (lane == 0) {
        const float hx = -0.5f * fmaf(cc, cc, fmaf(bb, bb, a*a));
        float d2 = -2.0f * (rb + hx);
        d2 = fmaxf(d2, 0.0f);
        const float w = __expf(-(d2 * d2) * (1.0f / 0.18f));   // 2*ALPHA^2
        t0 = w * d2;
        const float nx0 = xn[n*3+0], nx1 = xn[n*3+1], nx2 = xn[n*3+2];
        const float ny0 = yn[(size_t)bidx*3+0];
        const float ny1 = yn[(size_t)bidx*3+1];
        const float ny2 = yn[(size_t)bidx*3+2];
        const float nnx = fmaxf(sqrtf(nx0*nx0 + nx1*nx1 + nx2*nx2), 1e-6f);
        const float nny = fmaxf(sqrtf(ny0*ny0 + ny1*ny1 + ny2*ny2), 1e-6f);
        const float cosv = (nx0*ny0 + nx1*ny1 + nx2*ny2) / (nnx * nny);
        t1 = 1.0f - fabsf(cosv);
    }

    __shared__ float r0[256], r1[256];
    r0[threadIdx.x] = t0;
    r1[threadIdx.x] = t1;
    __syncthreads();
    for (int st = 128; st > 0; st >>= 1) {
        if (threadIdx.x < st) {
            r0[threadIdx.x] += r0[threadIdx.x + st];
            r1[threadIdx.x] += r1[threadIdx.x + st];
        }
        __syncthreads();
    }
    if (threadIdx.x == 0)
        wsB[blockIdx.y * gridDim.x + blockIdx.x] = make_float2(r0[0], r1[0]);
}

// ---------------------------------------------------------------------------
// Final deterministic reduction of the 2500 block partials.
// ---------------------------------------------------------------------------
__global__ __launch_bounds__(256) void reduce_final(
    const float2* __restrict__ wsB, int nblocks, float* __restrict__ out)
{
    __shared__ float r0[256], r1[256];
    const int t = threadIdx.x;
    float s0 = 0.f, s1 = 0.f;
    for (int i = t; i < nblocks; i += 256) {
        const float2 v = wsB[i];
        s0 += v.x;
        s1 += v.y;
    }
    r0[t] = s0; r1[t] = s1;
    __syncthreads();
    for (int st = 128; st > 0; st >>= 1) {
        if (t < st) { r0[t] += r0[t + st]; r1[t] += r1[t + st]; }
        __syncthreads();
    }
    if (t == 0) {
        out[0] = 0.5f * r0[0];                 // mean over B=2 of per-batch sums
        out[1] = r1[0] * (1.0f / 20000.0f);    // mean over B*N, both dirs
    }
}

extern "C" void kernel_launch(void* const* d_in, const int* in_sizes, int n_in,
                              void* d_out, int out_size, void* d_ws, size_t ws_size,
                              hipStream_t stream)
{
    const float* pred_pts = (const float*)d_in[0];
    const float* pred_nrm = (const float*)d_in[1];
    const float* targ_pts = (const float*)d_in[2];
    const float* targ_nrm = (const float*)d_in[3];
    float* out = (float*)d_out;

    // workspace carve (~16 MB of ~256 MB)
    unsigned short* ypk = (unsigned short*)d_ws;            // 4*316*512 u16
    unsigned short* xpk = ypk + (size_t)4 * NYT * 512;      // 4*320*512 u16
    float* wsM  = (float*)(xpk + (size_t)4 * NXT2 * 512);   // 4*79*10000 f32
    float2* wsB = (float2*)(wsM + (size_t)4 * NS * NPTS);   // 2500 float2

    const int PTOT = 4 * NYP + 4 * NXT2 * 32;               // pack threads
    pack_xy<<<(PTOT + 255) / 256, 256, 0, stream>>>(pred_pts, targ_pts, ypk, xpk);

    dim3 gA(10, NS, 4);                 // 10 x-groups (32 tiles) x 79 x 4
    knn_mfma<<<gA, 256, 0, stream>>>(ypk, xpk, wsM);

    dim3 gB(NPTS / 16, 4);              // 625 x 4
    finalize<<<gB, 256, 0, stream>>>(pred_pts, pred_nrm, targ_pts, targ_nrm,
                                     wsM, wsB);

    reduce_final<<<1, 256, 0, stream>>>(wsB, (NPTS / 16) * 4, out);
}

// Round 16
// 52.665 us; speedup vs baseline: 1.6518x; 1.4982x over previous
//
#include <hip/hip_runtime.h>
#include <math.h>

#define NPTS 10000
#define XPT 4              // x-points per thread (register-safe; XPT>=6 makes the
                           // compiler restructure/re-read LDS -- R3/R9 ~2x tax)
#define AXCH 10            // 10 * 256 * 4 = 10240 >= 10000
#define NS 40              // slices  (R2-measured fastest knn geometry)
#define SLICE 250          // NPTS / NS

// ---------------------------------------------------------------------------
// Pass A (R2 bench geometry, ~27us measured): per (combo, slice, x-chunk) max
// of m_j = dot(x,y_j) - 0.5*|y_j|^2 (equiv. min d2). All-scalar fmaf + max3;
// single 250-y LDS stage; broadcast b128 reads (conflict-free, ~8cyc/read).
// ---------------------------------------------------------------------------
__global__ __launch_bounds__(256) void knn_max(
    const float* __restrict__ pred_pts, const float* __restrict__ targ_pts,
    float* __restrict__ wsM)
{
    const int c   = blockIdx.z;
    const int dir = c >> 1, b = c & 1;
    const float* xp = (dir == 0 ? targ_pts : pred_pts) + (size_t)b * NPTS * 3;
    const float* yp = (dir == 0 ? pred_pts : targ_pts) + (size_t)b * NPTS * 3;
    const int s = blockIdx.y;
    const int base = blockIdx.x * (256 * XPT) + threadIdx.x;

    __shared__ float4 sy[SLICE];               // 4 KB

    float xx[XPT][3];
#pragma unroll
    for (int k = 0; k < XPT; ++k) {
        const int n = base + k * 256;
        const int nn = (n < NPTS) ? n : (NPTS - 1);   // clamp; discard on store
        xx[k][0] = xp[nn * 3 + 0];
        xx[k][1] = xp[nn * 3 + 1];
        xx[k][2] = xp[nn * 3 + 2];
    }
    float best[XPT];
#pragma unroll
    for (int k = 0; k < XPT; ++k) best[k] = -1e30f;

    const int js = s * SLICE;
    if (threadIdx.x < SLICE) {
        const int j = js + threadIdx.x;
        const float a  = yp[j * 3 + 0];
        const float bb = yp[j * 3 + 1];
        const float cc = yp[j * 3 + 2];
        // hy via explicit fmaf chain so finalize reproduces it bit-exactly.
        sy[threadIdx.x] =
            make_float4(a, bb, cc, -0.5f * fmaf(cc, cc, fmaf(bb, bb, a * a)));
    }
    __syncthreads();

#pragma unroll 4
    for (int j = 0; j < SLICE; j += 2) {
        const float4 Y0 = sy[j];               // broadcast: conflict-free
        const float4 Y1 = sy[j + 1];
#pragma unroll
        for (int k = 0; k < XPT; ++k) {
            const float ma = fmaf(xx[k][0], Y0.x,
                             fmaf(xx[k][1], Y0.y,
                             fmaf(xx[k][2], Y0.z, Y0.w)));
            const float mb = fmaf(xx[k][0], Y1.x,
                             fmaf(xx[k][1], Y1.y,
                             fmaf(xx[k][2], Y1.z, Y1.w)));
            best[k] = fmaxf(fmaxf(best[k], ma), mb);   // -> v_max3_f32
        }
    }

#pragma unroll
    for (int k = 0; k < XPT; ++k) {
        const int n = base + k * 256;
        if (n < NPTS)
            wsM[((size_t)c * NS + s) * NPTS + n] = best[k];   // coalesced
    }
}

// ---------------------------------------------------------------------------
// Pass B (R3/R10-proven, ~7us measured): 8-lane group per x-point.
//   1) slice-select: 5 strided loads, 3-step butterfly, tie -> smaller s.
//   2) lane-parallel rescan of the winning slice (32 iters), identical fmaf
//      chain -> bit-consistent with pass A; strict > ascending j + cross-lane
//      tie -> smaller j == exact first-occurrence argmax.
//   3) lane 0: Welsch + normal-cosine terms; block-reduce to float2.
// ---------------------------------------------------------------------------
__global__ __launch_bounds__(256) void finalize(
    const float* __restrict__ pred_pts, const float* __restrict__ pred_nrm,
    const float* __restrict__ targ_pts, const float* __restrict__ targ_nrm,
    const float* __restrict__ wsM, float2* __restrict__ wsB)
{
    const int c   = blockIdx.y;
    const int dir = c >> 1, b = c & 1;
    const float* xp = (dir == 0 ? targ_pts : pred_pts) + (size_t)b * NPTS * 3;
    const float* xn = (dir == 0 ? targ_nrm : pred_nrm) + (size_t)b * NPTS * 3;
    const float* yp = (dir == 0 ? pred_pts : targ_pts) + (size_t)b * NPTS * 3;
    const float* yn = (dir == 0 ? pred_nrm : targ_nrm) + (size_t)b * NPTS * 3;

    const int lane = threadIdx.x & 7;
    const int n = blockIdx.x * 32 + (threadIdx.x >> 3);

    float t0 = 0.f, t1 = 0.f;
    if (n < NPTS) {
        // 1) slice select
        float bm = -1e30f;
        int   bs = 1 << 30;
        for (int s = lane; s < NS; s += 8) {
            const float m = wsM[((size_t)c * NS + s) * NPTS + n];
            if (m > bm) { bm = m; bs = s; }    // in-lane: s ascending
        }
#pragma unroll
        for (int w = 1; w < 8; w <<= 1) {
            const float mo = __shfl_xor(bm, w);
            const int   so = __shfl_xor(bs, w);
            if (mo > bm || (mo == bm && so < bs)) { bm = mo; bs = so; }
        }
        // 2) rescan winning slice
        const float a  = xp[n * 3 + 0];
        const float bb = xp[n * 3 + 1];
        const float cc = xp[n * 3 + 2];
        const int j0 = bs * SLICE;
        float rb = -1e30f;
        int bidx = 1 << 30;
        for (int j = j0 + lane; j < j0 + SLICE; j += 8) {
            const float ya = yp[j * 3 + 0];
            const float yb = yp[j * 3 + 1];
            const float yc = yp[j * 3 + 2];
            const float hy = -0.5f * fmaf(yc, yc, fmaf(yb, yb, ya * ya));
            const float m  = fmaf(a, ya, fmaf(bb, yb, fmaf(cc, yc, hy)));
            if (m > rb) { rb = m; bidx = j; }  // in-lane: j ascending
        }
#pragma unroll
        for (int w = 1; w < 8; w <<= 1) {
            const float mo = __shfl_xor(rb, w);
            const int   jo = __shfl_xor(bidx, w);
            if (mo > rb || (mo == rb && jo < bidx)) { rb = mo; bidx = jo; }
        }
        // 3) terms on lane 0 only
        if (lane == 0) {
            const float hx = -0.5f * fmaf(cc, cc, fmaf(bb, bb, a * a));
            float d2 = -2.0f * (rb + hx);
            d2 = fmaxf(d2, 0.0f);
            const float w = __expf(-(d2 * d2) * (1.0f / 0.18f));  // 2*ALPHA^2
            t0 = w * d2;
            const float nx0 = xn[n * 3 + 0], nx1 = xn[n * 3 + 1], nx2 = xn[n * 3 + 2];
            const float ny0 = yn[(size_t)bidx * 3 + 0];
            const float ny1 = yn[(size_t)bidx * 3 + 1];
            const float ny2 = yn[(size_t)bidx * 3 + 2];
            const float nnx = fmaxf(sqrtf(nx0 * nx0 + nx1 * nx1 + nx2 * nx2), 1e-6f);
            const float nny = fmaxf(sqrtf(ny0 * ny0 + ny1 * ny1 + ny2 * ny2), 1e-6f);
            const float cosv = (nx0 * ny0 + nx1 * ny1 + nx2 * ny2) / (nnx * nny);
            t1 = 1.0f - fabsf(cosv);
        }
    }

    __shared__ float r0[256], r1[256];
    r0[threadIdx.x] = t0;
    r1[threadIdx.x] = t1;
    __syncthreads();
    for (int st = 128; st > 0; st >>= 1) {
        if (threadIdx.x < st) {
            r0[threadIdx.x] += r0[threadIdx.x + st];
            r1[threadIdx.x] += r1[threadIdx.x + st];
        }
        __syncthreads();
    }
    if (threadIdx.x == 0)
        wsB[blockIdx.y * gridDim.x + blockIdx.x] = make_float2(r0[0], r1[0]);
}

// ---------------------------------------------------------------------------
// Final deterministic reduction of the 1252 block partials.
// ---------------------------------------------------------------------------
__global__ __launch_bounds__(256) void reduce_final(
    const float2* __restrict__ wsB, int nblocks, float* __restrict__ out)
{
    __shared__ float r0[256], r1[256];
    const int t = threadIdx.x;
    float s0 = 0.f, s1 = 0.f;
    for (int i = t; i < nblocks; i += 256) {
        const float2 v = wsB[i];
        s0 += v.x;
        s1 += v.y;
    }
    r0[t] = s0; r1[t] = s1;
    __syncthreads();
    for (int st = 128; st > 0; st >>= 1) {
        if (t < st) { r0[t] += r0[t + st]; r1[t] += r1[t + st]; }
        __syncthreads();
    }
    if (t == 0) {
        out[0] = 0.5f * r0[0];                 // mean over B=2 of per-batch sums
        out[1] = r1[0] * (1.0f / 20000.0f);    // mean over B*N, both dirs
    }
}

extern "C" void kernel_launch(void* const* d_in, const int* in_sizes, int n_in,
                              void* d_out, int out_size, void* d_ws, size_t ws_size,
                              hipStream_t stream)
{
    const float* pred_pts = (const float*)d_in[0];
    const float* pred_nrm = (const float*)d_in[1];
    const float* targ_pts = (const float*)d_in[2];
    const float* targ_nrm = (const float*)d_in[3];
    float* out = (float*)d_out;

    const int BXCH = (NPTS + 31) / 32;   // 313 blocks per combo in pass B

    float* wsM = (float*)d_ws;           // 4*NS*NPTS f32 = 6.4 MB
    float2* wsB = (float2*)((char*)d_ws + (size_t)4 * NS * NPTS * sizeof(float));

    dim3 gA(AXCH, NS, 4);                // 1600 blocks (R2-measured geometry)
    knn_max<<<gA, 256, 0, stream>>>(pred_pts, targ_pts, wsM);

    dim3 gB(BXCH, 4);
    finalize<<<gB, 256, 0, stream>>>(pred_pts, pred_nrm, targ_pts, targ_nrm,
                                     wsM, wsB);

    reduce_final<<<1, 256, 0, stream>>>(wsB, BXCH * 4, out);
}

// Round 17
// 50.757 us; speedup vs baseline: 1.7138x; 1.0376x over previous
//
#include <hip/hip_runtime.h>
#include <math.h>

#define NPTS 10000
#define XPT 8              // x-points per thread; NEEDS __launch_bounds__(256,4)
                           // (128-reg budget). Default bounds cap VGPR~24-32 and
                           // cause the R3/R9 "tax". R8 proved (256,4) is clean.
#define AXCH 5             // 5 * 256 * 8 = 10240 >= 10000
#define NS 50              // slices
#define SLICE 200          // NPTS / NS

// ---------------------------------------------------------------------------
// Pass A: per (combo, slice, x-chunk) max of m_j = dot(x,y_j) - 0.5*|y_j|^2
// (equiv. min d2). All-scalar fmaf + max3. XPT=8 halves the per-CU LDS
// broadcast traffic vs XPT=4 (the R16-measured bottleneck half); explicit
// 2-ahead register prefetch of the y-pair breaks the LDS->FMA wait chain
// (R16 showed VALU and LDS times SUMMING, not overlapping).
// ---------------------------------------------------------------------------
__global__ __launch_bounds__(256, 4) void knn_max(
    const float* __restrict__ pred_pts, const float* __restrict__ targ_pts,
    float* __restrict__ wsM)
{
    const int c   = blockIdx.z;
    const int dir = c >> 1, b = c & 1;
    const float* xp = (dir == 0 ? targ_pts : pred_pts) + (size_t)b * NPTS * 3;
    const float* yp = (dir == 0 ? pred_pts : targ_pts) + (size_t)b * NPTS * 3;
    const int s = blockIdx.y;
    const int base = blockIdx.x * (256 * XPT) + threadIdx.x;

    __shared__ float4 sy[SLICE + 2];           // +2 pad for prefetch overrun

    float xx[XPT][3];
#pragma unroll
    for (int k = 0; k < XPT; ++k) {
        const int n = base + k * 256;
        const int nn = (n < NPTS) ? n : (NPTS - 1);   // clamp; discard on store
        xx[k][0] = xp[nn * 3 + 0];
        xx[k][1] = xp[nn * 3 + 1];
        xx[k][2] = xp[nn * 3 + 2];
    }
    float best[XPT];
#pragma unroll
    for (int k = 0; k < XPT; ++k) best[k] = -1e30f;

    const int js = s * SLICE;
    if (threadIdx.x < SLICE) {
        const int j = js + threadIdx.x;
        const float a  = yp[j * 3 + 0];
        const float bb = yp[j * 3 + 1];
        const float cc = yp[j * 3 + 2];
        // hy via explicit fmaf chain so finalize reproduces it bit-exactly.
        sy[threadIdx.x] =
            make_float4(a, bb, cc, -0.5f * fmaf(cc, cc, fmaf(bb, bb, a * a)));
    } else if (threadIdx.x < SLICE + 2) {
        sy[threadIdx.x] = make_float4(0.f, 0.f, 0.f, 0.f);   // pad
    }
    __syncthreads();

    float4 Ya = sy[0], Yb = sy[1];             // prime the prefetch pipeline
#pragma unroll 2
    for (int j = 0; j < SLICE; j += 2) {
        const float4 Yc = sy[j + 2];           // prefetch next pair (pad-safe)
        const float4 Yd = sy[j + 3];
#pragma unroll
        for (int k = 0; k < XPT; ++k) {
            const float ma = fmaf(xx[k][0], Ya.x,
                             fmaf(xx[k][1], Ya.y,
                             fmaf(xx[k][2], Ya.z, Ya.w)));
            const float mb = fmaf(xx[k][0], Yb.x,
                             fmaf(xx[k][1], Yb.y,
                             fmaf(xx[k][2], Yb.z, Yb.w)));
            best[k] = fmaxf(fmaxf(best[k], ma), mb);   // -> v_max3_f32
        }
        Ya = Yc; Yb = Yd;
    }

#pragma unroll
    for (int k = 0; k < XPT; ++k) {
        const int n = base + k * 256;
        if (n < NPTS)
            wsM[((size_t)c * NS + s) * NPTS + n] = best[k];   // coalesced f32
    }
}

// ---------------------------------------------------------------------------
// Pass B (R3/R10/R16-proven shape): 8-lane group per x-point.
//   1) slice-select: 7 strided loads, 3-step butterfly, tie -> smaller s.
//   2) lane-parallel rescan of the winning slice (25 iters), identical fmaf
//      chain -> bit-consistent with pass A; strict > ascending j + cross-lane
//      tie -> smaller j == exact first-occurrence argmax.
//   3) lane 0: Welsch + normal-cosine terms; block-reduce to float2.
// ---------------------------------------------------------------------------
__global__ __launch_bounds__(256) void finalize(
    const float* __restrict__ pred_pts, const float* __restrict__ pred_nrm,
    const float* __restrict__ targ_pts, const float* __restrict__ targ_nrm,
    const float* __restrict__ wsM, float2* __restrict__ wsB)
{
    const int c   = blockIdx.y;
    const int dir = c >> 1, b = c & 1;
    const float* xp = (dir == 0 ? targ_pts : pred_pts) + (size_t)b * NPTS * 3;
    const float* xn = (dir == 0 ? targ_nrm : pred_nrm) + (size_t)b * NPTS * 3;
    const float* yp = (dir == 0 ? pred_pts : targ_pts) + (size_t)b * NPTS * 3;
    const float* yn = (dir == 0 ? pred_nrm : targ_nrm) + (size_t)b * NPTS * 3;

    const int lane = threadIdx.x & 7;
    const int n = blockIdx.x * 32 + (threadIdx.x >> 3);

    float t0 = 0.f, t1 = 0.f;
    if (n < NPTS) {
        // 1) slice select
        float bm = -1e30f;
        int   bs = 1 << 30;
        for (int s = lane; s < NS; s += 8) {
            const float m = wsM[((size_t)c * NS + s) * NPTS + n];
            if (m > bm) { bm = m; bs = s; }    // in-lane: s ascending
        }
#pragma unroll
        for (int w = 1; w < 8; w <<= 1) {
            const float mo = __shfl_xor(bm, w);
            const int   so = __shfl_xor(bs, w);
            if (mo > bm || (mo == bm && so < bs)) { bm = mo; bs = so; }
        }
        // 2) rescan winning slice
        const float a  = xp[n * 3 + 0];
        const float bb = xp[n * 3 + 1];
        const float cc = xp[n * 3 + 2];
        const int j0 = bs * SLICE;
        float rb = -1e30f;
        int bidx = 1 << 30;
        for (int j = j0 + lane; j < j0 + SLICE; j += 8) {
            const float ya = yp[j * 3 + 0];
            const float yb = yp[j * 3 + 1];
            const float yc = yp[j * 3 + 2];
            const float hy = -0.5f * fmaf(yc, yc, fmaf(yb, yb, ya * ya));
            const float m  = fmaf(a, ya, fmaf(bb, yb, fmaf(cc, yc, hy)));
            if (m > rb) { rb = m; bidx = j; }  // in-lane: j ascending
        }
#pragma unroll
        for (int w = 1; w < 8; w <<= 1) {
            const float mo = __shfl_xor(rb, w);
            const int   jo = __shfl_xor(bidx, w);
            if (mo > rb || (mo == rb && jo < bidx)) { rb = mo; bidx = jo; }
        }
        // 3) terms on lane 0 only
        if (lane == 0) {
            const float hx = -0.5f * fmaf(cc, cc, fmaf(bb, bb, a * a));
            float d2 = -2.0f * (rb + hx);
            d2 = fmaxf(d2, 0.0f);
            const float w = __expf(-(d2 * d2) * (1.0f / 0.18f));  // 2*ALPHA^2
            t0 = w * d2;
            const float nx0 = xn[n * 3 + 0], nx1 = xn[n * 3 + 1], nx2 = xn[n * 3 + 2];
            const float ny0 = yn[(size_t)bidx * 3 + 0];
            const float ny1 = yn[(size_t)bidx * 3 + 1];
            const float ny2 = yn[(size_t)bidx * 3 + 2];
            const float nnx = fmaxf(sqrtf(nx0 * nx0 + nx1 * nx1 + nx2 * nx2), 1e-6f);
            const float nny = fmaxf(sqrtf(ny0 * ny0 + ny1 * ny1 + ny2 * ny2), 1e-6f);
            const float cosv = (nx0 * ny0 + nx1 * ny1 + nx2 * ny2) / (nnx * nny);
            t1 = 1.0f - fabsf(cosv);
        }
    }

    __shared__ float r0[256], r1[256];
    r0[threadIdx.x] = t0;
    r1[threadIdx.x] = t1;
    __syncthreads();
    for (int st = 128; st > 0; st >>= 1) {
        if (threadIdx.x < st) {
            r0[threadIdx.x] += r0[threadIdx.x + st];
            r1[threadIdx.x] += r1[threadIdx.x + st];
        }
        __syncthreads();
    }
    if (threadIdx.x == 0)
        wsB[blockIdx.y * gridDim.x + blockIdx.x] = make_float2(r0[0], r1[0]);
}

// ---------------------------------------------------------------------------
// Final deterministic reduction of the 1252 block partials.
// ---------------------------------------------------------------------------
__global__ __launch_bounds__(256) void reduce_final(
    const float2* __restrict__ wsB, int nblocks, float* __restrict__ out)
{
    __shared__ float r0[256], r1[256];
    const int t = threadIdx.x;
    float s0 = 0.f, s1 = 0.f;
    for (int i = t; i < nblocks; i += 256) {
        const float2 v = wsB[i];
        s0 += v.x;
        s1 += v.y;
    }
    r0[t] = s0; r1[t] = s1;
    __syncthreads();
    for (int st = 128; st > 0; st >>= 1) {
        if (t < st) { r0[t] += r0[t + st]; r1[t] += r1[t + st]; }
        __syncthreads();
    }
    if (t == 0) {
        out[0] = 0.5f * r0[0];                 // mean over B=2 of per-batch sums
        out[1] = r1[0] * (1.0f / 20000.0f);    // mean over B*N, both dirs
    }
}

extern "C" void kernel_launch(void* const* d_in, const int* in_sizes, int n_in,
                              void* d_out, int out_size, void* d_ws, size_t ws_size,
                              hipStream_t stream)
{
    const float* pred_pts = (const float*)d_in[0];
    const float* pred_nrm = (const float*)d_in[1];
    const float* targ_pts = (const float*)d_in[2];
    const float* targ_nrm = (const float*)d_in[3];
    float* out = (float*)d_out;

    const int BXCH = (NPTS + 31) / 32;   // 313 blocks per combo in pass B

    float* wsM = (float*)d_ws;           // 4*NS*NPTS f32 = 8.0 MB
    float2* wsB = (float2*)((char*)d_ws + (size_t)4 * NS * NPTS * sizeof(float));

    dim3 gA(AXCH, NS, 4);                // 1000 blocks, 15.6 waves/CU
    knn_max<<<gA, 256, 0, stream>>>(pred_pts, targ_pts, wsM);

    dim3 gB(BXCH, 4);
    finalize<<<gB, 256, 0, stream>>>(pred_pts, pred_nrm, targ_pts, targ_nrm,
                                     wsM, wsB);

    reduce_final<<<1, 256, 0, stream>>>(wsB, BXCH * 4, out);
}